// Round 3
// baseline (17530.098 us; speedup 1.0000x reference)
//
#include <hip/hip_runtime.h>
#include <stdint.h>

typedef short short8 __attribute__((ext_vector_type(8)));
typedef float float4v __attribute__((ext_vector_type(4)));
typedef uint32_t u32;
typedef uint64_t u64;
typedef uint32_t u32x2 __attribute__((ext_vector_type(2)));
typedef uint32_t u32x4 __attribute__((ext_vector_type(4)));

#define NSTEPS 512

__device__ __forceinline__ unsigned short f2bf(float f) {
  unsigned u = __builtin_bit_cast(unsigned, f);
  u += 0x7fffu + ((u >> 16) & 1u);
  return (unsigned short)(u >> 16);
}

// ---- XCD-local transport: MUBUF atomics at the L2 coherence point -------
// buffer_atomic ops execute at L2 (never L1-cached); sc0 on an atomic =
// return-old (documented for gfx950 MUBUF in the ISA ref §5). This avoids
// any reliance on undocumented global_*-op cache flags (suspected cause of
// the round-1/2 build failures) and on L1 write policy.
__device__ __forceinline__ u32x4 make_srsrc(const void* p, u32 bytes) {
  u32x4 r;
  u64 a = (u64)p;
  r.x = (u32)a;
  r.y = (u32)(a >> 32);   // stride=0
  r.z = bytes;            // num_records in bytes
  r.w = 0x00020000u;      // raw untyped dword access
  return r;
}
// 64-bit L2-atomic read (add 0, return old). Caller drains vmcnt.
#define BLD64(dst, voff, OFFSTR, rs)                                         \
  do {                                                                       \
    (dst).x = 0u; (dst).y = 0u;                                              \
    asm volatile("buffer_atomic_add_x2 %0, %1, %2, 0 offen offset:" OFFSTR   \
                 " sc0"                                                      \
                 : "+v"(dst) : "v"(voff), "s"(rs) : "memory");               \
  } while (0)

__device__ __forceinline__ u32 l2_read32(u32x4 rs, u32 voff) {
  u32 z = 0;
  asm volatile("buffer_atomic_add %0, %1, %2, 0 offen sc0\n\t"
               "s_waitcnt vmcnt(0)"
               : "+v"(z) : "v"(voff), "s"(rs) : "memory");
  return z;
}
__device__ __forceinline__ void l2_write32(u32x4 rs, u32 voff, u32 v) {
  asm volatile("buffer_atomic_swap %0, %1, %2, 0 offen"
               :: "v"(v), "v"(voff), "s"(rs) : "memory");
}

// xbf layout (A-fragment swizzled): short8[ ((l*4+g)*16 + kk)*64 + lane ]
__global__ __launch_bounds__(256) void xprep_kernel(const float* __restrict__ x,
                                                    short* __restrict__ xbf) {
  unsigned tid = blockIdx.x * 256u + threadIdx.x;   // 2,097,152 total
  unsigned lane = tid & 63u;
  unsigned kk   = (tid >> 6) & 15u;
  unsigned g    = (tid >> 10) & 3u;
  unsigned l    = tid >> 12;
  unsigned m = lane & 15u, qo = lane >> 4;
  const float* src = x + (((size_t)(g * 16u + m) * 512u + l) * 512u + kk * 32u + qo * 8u);
  float4 a  = ((const float4*)src)[0];
  float4 b2 = ((const float4*)src)[1];
  short8 v;
  v[0] = (short)f2bf(a.x);  v[1] = (short)f2bf(a.y);
  v[2] = (short)f2bf(a.z);  v[3] = (short)f2bf(a.w);
  v[4] = (short)f2bf(b2.x); v[5] = (short)f2bf(b2.y);
  v[6] = (short)f2bf(b2.z); v[7] = (short)f2bf(b2.w);
  *(short8*)(xbf + (size_t)tid * 8u) = v;
}

// Persistent recurrent kernel with self-verifying XCD-local sync.
// grid=256: r=b&7 (expected XCD under round-robin); odd r exit; g=r>>1,
// c=b>>3. Prologue: (1) vote XCC_ID over sc1 (proven transport); (2) if
// uniform, PROBE the L2-atomic transport end-to-end (each chunk swaps a
// token into its flag; peers must observe it); (3) consensus over sc1.
// Only a group whose probe SUCCEEDED uses L2-local flags/state; anything
// else (wrong mapping, lying XCC_ID, broken flags, bad SRSRC) falls back
// to the baseline sc1 path. Probe doubles as flag initializer, so replays
// never depend on memset-vs-dirty-L2 coherence. State regions are keyed by
// (xcd,g) so dirty lines from one XCD can never alias another replay's.
__global__ __launch_bounds__(256, 1) void lstm_persist(
    const float* __restrict__ Wfp, const float* __restrict__ bfp,
    const float* __restrict__ Wip, const float* __restrict__ bip,
    const float* __restrict__ Wop, const float* __restrict__ bop,
    const float* __restrict__ Whp, const float* __restrict__ bhp,
    const short* __restrict__ xbf,
    short* __restrict__ sbufL,       // 32 regions x [2][16][64][8] bf16
    short* __restrict__ sbufM,       // 4 regions (sc1 fallback), same shape
    u32* __restrict__ arrL,          // 32 regions x 32 flags (L2-local)
    u32* __restrict__ arrM,          // 4 x 32 flags (sc1)
    u32* __restrict__ vote,          // [4][32] xcd+1
    u32* __restrict__ vote2,         // [4][32] probe consensus (1 ok / 2 fail)
    float* __restrict__ out)         // [64][512][512] fp32
{
  __shared__ float gl[4 * 16 * 17];  // [gate][seq][h(+pad)]
  __shared__ int s_ok[4];

  const unsigned b = blockIdx.x;
  const unsigned r = b & 7u;
  if (r & 1u) return;                // spare residues exit whole-block
  const unsigned g = r >> 1;
  const unsigned c = b >> 3;
  const unsigned t = threadIdx.x;
  const unsigned w = t >> 6;
  const unsigned lane = t & 63u;
  const unsigned m = lane & 15u, qo = lane >> 4;

  // ---- vote phase (sc1, baseline-proven transport) ----
  if (t == 0) {
    u32 xcd = (u32)__builtin_amdgcn_s_getreg((31u << 11) | 20u) & 7u; // XCC_ID
    __hip_atomic_store(vote + g * 32u + c, xcd + 1u, __ATOMIC_RELAXED,
                       __HIP_MEMORY_SCOPE_AGENT);
  }
  u32 myv = 0;
  {
    const u32* vp = vote + g * 32u + (lane & 31u);
    long sp = 0;
    while ((myv = __hip_atomic_load(vp, __ATOMIC_RELAXED,
                                    __HIP_MEMORY_SCOPE_AGENT)) == 0u) {
      __builtin_amdgcn_s_sleep(2);
      if (++sp > 30000000L) break;
    }
  }
  u32 v0 = (u32)__builtin_amdgcn_readfirstlane((int)myv);
  int uniform = __all((int)(myv == v0)) && (v0 >= 1u) && (v0 <= 8u);
  s_ok[w] = uniform;
  __syncthreads();
  uniform = s_ok[0] & s_ok[1] & s_ok[2] & s_ok[3];
  __syncthreads();

  const unsigned region = uniform ? ((v0 - 1u) * 4u + g) : 0u;
  short* sbL = sbufL + (size_t)region * 16384u;       // 32 KiB region
  u32x4 srsD = make_srsrc(sbL, 32768u);
  u32x4 srsF = make_srsrc(arrL + region * 32u, 128u);
  short* sbM = sbufM + (size_t)g * 16384u;
  u32*   aM  = arrM + g * 32u;

  // ---- probe + consensus ----
  int local = 0;
  if (uniform) {
    if (t == 0) {
      l2_write32(srsF, c * 4u, 1000u + c);
      asm volatile("s_waitcnt vmcnt(0)" ::: "memory");
    }
    int ok = 1;
    {
      u32 vo = (lane & 31u) * 4u;
      u32 want = 1000u + (lane & 31u);
      long sp = 0;
      while (l2_read32(srsF, vo) != want) {
        __builtin_amdgcn_s_sleep(2);
        if (++sp > 200000L) { ok = 0; break; }
      }
    }
    ok = __all(ok);
    s_ok[w] = ok;
    __syncthreads();
    int blk_ok = s_ok[0] & s_ok[1] & s_ok[2] & s_ok[3];
    if (t == 0)
      __hip_atomic_store(vote2 + g * 32u + c, blk_ok ? 1u : 2u,
                         __ATOMIC_RELAXED, __HIP_MEMORY_SCOPE_AGENT);
    u32 pv = 0;
    {
      const u32* vp = vote2 + g * 32u + (lane & 31u);
      long sp = 0;
      while ((pv = __hip_atomic_load(vp, __ATOMIC_RELAXED,
                                     __HIP_MEMORY_SCOPE_AGENT)) == 0u) {
        __builtin_amdgcn_s_sleep(2);
        if (++sp > 30000000L) { pv = 2u; break; }
      }
    }
    int lw = __all((int)(pv == 1u));
    __syncthreads();
    s_ok[w] = lw;
    __syncthreads();
    local = s_ok[0] & s_ok[1] & s_ok[2] & s_ok[3];
    // reset probe tokens -> 0 (doubles as cross-replay flag init); wait
    // until all tokens are gone (< 1000 accepts early step-posts too).
    if (local) {
      if (t == 0) {
        l2_write32(srsF, c * 4u, 0u);
        asm volatile("s_waitcnt vmcnt(0)" ::: "memory");
      }
      u32 vo = (lane & 31u) * 4u;
      long sp = 0;
      while (l2_read32(srsF, vo) >= 1000u) {
        __builtin_amdgcn_s_sleep(2);
        if (++sp > 10000000L) break;
      }
    }
  }

  const float* Wsrc = (w == 0) ? Wfp : (w == 1) ? Wip : (w == 2) ? Wop : Whp;
  const float* bsrc = (w == 0) ? bfp : (w == 1) ? bip : (w == 2) ? bop : bhp;

  // ---- one-time: this wave's B-fragments (W rows c*16+[0,16)) in registers.
  short8 wsf[16], wnf[16];
  {
    const float* wrow = Wsrc + (size_t)(c * 16u + m) * 1024u + qo * 8u;
#pragma unroll
    for (int kk = 0; kk < 16; kk++) {
      const float* p = wrow + kk * 32;
      short8 vs, vn;
#pragma unroll
      for (int j = 0; j < 8; j++) {
        vs[j] = (short)f2bf(p[j]);          // W_short = cols [0,512)
        vn[j] = (short)f2bf(p[512 + j]);    // W_now   = cols [512,1024)
      }
      wsf[kk] = vs;
      wnf[kk] = vn;
    }
  }
  const float bias = bsrc[c * 16u + m];

  // elementwise ownership: thread t <-> (seq mm, h hh); state in register.
  const unsigned mm = t >> 4, hh = t & 15u;
  float longv = 0.f;
  float* outp = out + (size_t)(g * 16u + mm) * (512u * 512u) + (c * 16u + hh);

  // store slot (u32 = 2 adjacent bf16), even threads only
  unsigned slot_off;                 // u32 index within a 16 KiB slot
  {
    unsigned k   = c * 16u + hh;     // hh even for storing threads
    unsigned kk2 = k >> 5;
    unsigned lw2 = ((k >> 3) & 3u) * 16u + mm;
    unsigned jj  = k & 7u;
    slot_off = (kk2 * 64u + lw2) * 4u + (jj >> 1);
  }
  u32* sdstM = (u32*)sbM + slot_off;

  for (int l = 0; l < NSTEPS; l++) {
    // ---- x-part: independent of peers, runs before the wait.
    const short8* xt = (const short8*)xbf + ((size_t)(l * 4 + g) * 16u) * 64u + lane;
    short8 xa[16];
#pragma unroll
    for (int kk = 0; kk < 16; kk++) xa[kk] = xt[(size_t)kk * 64u];

    float4v acc[4];
    {
      float4v bb = {bias, bias, bias, bias};
      float4v zz = {0.f, 0.f, 0.f, 0.f};
      acc[0] = bb; acc[1] = zz; acc[2] = zz; acc[3] = zz;
    }
#pragma unroll
    for (int kk = 0; kk < 16; kk++)
      acc[kk & 3] = __builtin_amdgcn_mfma_f32_16x16x32_bf16(xa[kk], wnf[kk], acc[kk & 3], 0, 0, 0);

    if (l > 0) {
      // ---- wait for all 32 chunks to post step l-1.
      if (lane < 32u) {
        long spins = 0;
        if (local) {
          u32 vo = lane * 4u;
          while (l2_read32(srsF, vo) < (u32)l) {
            __builtin_amdgcn_s_sleep(1);
            if (++spins > (100LL * 1000 * 1000)) break;
          }
        } else {
          const u32* fp = aM + lane;
          while (__hip_atomic_load(fp, __ATOMIC_RELAXED,
                                   __HIP_MEMORY_SCOPE_AGENT) < (u32)l) {
            __builtin_amdgcn_s_sleep(1);
            if (++spins > (100LL * 1000 * 1000)) break;
          }
        }
      }

      // ---- recurrent part: short^{l-1} A-fragments.
      u32x2 tmp2[32];
      const unsigned slotB = ((unsigned)(l - 1) & 1u) * 16384u;
      if (local) {
        u32 vo0 = slotB + lane * 16u;
        u32 vo1 = vo0 + 4096u;
        u32 vo2 = vo0 + 8192u;
        u32 vo3 = vo0 + 12288u;
        BLD64(tmp2[0],  vo0, "0", srsD);    BLD64(tmp2[1],  vo0, "8", srsD);
        BLD64(tmp2[2],  vo0, "1024", srsD); BLD64(tmp2[3],  vo0, "1032", srsD);
        BLD64(tmp2[4],  vo0, "2048", srsD); BLD64(tmp2[5],  vo0, "2056", srsD);
        BLD64(tmp2[6],  vo0, "3072", srsD); BLD64(tmp2[7],  vo0, "3080", srsD);
        BLD64(tmp2[8],  vo1, "0", srsD);    BLD64(tmp2[9],  vo1, "8", srsD);
        BLD64(tmp2[10], vo1, "1024", srsD); BLD64(tmp2[11], vo1, "1032", srsD);
        BLD64(tmp2[12], vo1, "2048", srsD); BLD64(tmp2[13], vo1, "2056", srsD);
        BLD64(tmp2[14], vo1, "3072", srsD); BLD64(tmp2[15], vo1, "3080", srsD);
        BLD64(tmp2[16], vo2, "0", srsD);    BLD64(tmp2[17], vo2, "8", srsD);
        BLD64(tmp2[18], vo2, "1024", srsD); BLD64(tmp2[19], vo2, "1032", srsD);
        BLD64(tmp2[20], vo2, "2048", srsD); BLD64(tmp2[21], vo2, "2056", srsD);
        BLD64(tmp2[22], vo2, "3072", srsD); BLD64(tmp2[23], vo2, "3080", srsD);
        BLD64(tmp2[24], vo3, "0", srsD);    BLD64(tmp2[25], vo3, "8", srsD);
        BLD64(tmp2[26], vo3, "1024", srsD); BLD64(tmp2[27], vo3, "1032", srsD);
        BLD64(tmp2[28], vo3, "2048", srsD); BLD64(tmp2[29], vo3, "2056", srsD);
        BLD64(tmp2[30], vo3, "3072", srsD); BLD64(tmp2[31], vo3, "3080", srsD);
      } else {
        const u64* stM = (const u64*)sbM + (size_t)(slotB >> 3) + (size_t)lane * 2u;
#pragma unroll
        for (int kk = 0; kk < 16; kk++) {
          u64 a = __hip_atomic_load(stM + (size_t)kk * 128u, __ATOMIC_RELAXED,
                                    __HIP_MEMORY_SCOPE_AGENT);
          u64 bqq = __hip_atomic_load(stM + (size_t)kk * 128u + 1u, __ATOMIC_RELAXED,
                                      __HIP_MEMORY_SCOPE_AGENT);
          tmp2[2 * kk]     = __builtin_bit_cast(u32x2, a);
          tmp2[2 * kk + 1] = __builtin_bit_cast(u32x2, bqq);
        }
      }
      asm volatile("s_waitcnt vmcnt(0)" ::: "memory");
      __builtin_amdgcn_sched_barrier(0);

#pragma unroll
      for (int kk = 0; kk < 16; kk++) {
        struct { u32x2 a, bq; } p = { tmp2[2 * kk], tmp2[2 * kk + 1] };
        short8 sa = __builtin_bit_cast(short8, p);
        acc[kk & 3] = __builtin_amdgcn_mfma_f32_16x16x32_bf16(sa, wsf[kk], acc[kk & 3], 0, 0, 0);
      }
    }

    float4v tot = (acc[0] + acc[1]) + (acc[2] + acc[3]);
    // C/D layout: col = lane&15 (gate row/h), row = qo*4 + r (seq)
#pragma unroll
    for (int rr = 0; rr < 4; rr++)
      gl[(w * 16u + qo * 4u + (unsigned)rr) * 17u + m] = tot[rr];
    __syncthreads();

    // ---- elementwise update (all 256 threads: 16 seq x 16 h)
    float fg = gl[(0 * 16 + mm) * 17 + hh];
    float ig = gl[(1 * 16 + mm) * 17 + hh];
    float og = gl[(2 * 16 + mm) * 17 + hh];
    float hg = gl[(3 * 16 + mm) * 17 + hh];   // no activation on h (matches ref)
    fg = 1.f / (1.f + __expf(-fg));
    ig = 1.f / (1.f + __expf(-ig));
    og = 1.f / (1.f + __expf(-og));
    longv = fg * longv + ig * hg;
    float e  = __expf(-2.f * fabsf(longv));
    float th = (1.f - e) / (1.f + e);
    th = (longv < 0.f) ? -th : th;
    float sh = og * th;

    // pack adjacent-h pair into u32, even threads store
    unsigned short mybf = f2bf(sh);
    float shn = __shfl_xor(sh, 1);
    if ((t & 1u) == 0u) {
      u32 val = (u32)mybf | ((u32)f2bf(shn) << 16);
      if (local) {
        u32 vo = ((unsigned)(l & 1)) * 16384u + slot_off * 4u;
        l2_write32(srsD, vo, val);
      } else {
        __hip_atomic_store(sdstM + ((size_t)((unsigned)l & 1u)) * 4096u, val,
                           __ATOMIC_RELAXED, __HIP_MEMORY_SCOPE_AGENT);
      }
    }
    // data-store ack before the barrier; then flag post.
    asm volatile("s_waitcnt vmcnt(0)" ::: "memory");
    __syncthreads();
    if (t == 0) {
      if (local) {
        l2_write32(srsF, c * 4u, (u32)(l + 1));
      } else {
        __hip_atomic_store(aM + c, (u32)(l + 1), __ATOMIC_RELAXED,
                           __HIP_MEMORY_SCOPE_AGENT);
      }
    }

    // output store AFTER the flag post: keeps it off the sync critical path
    outp[(size_t)l * 512u] = sh;
  }
}

extern "C" void kernel_launch(void* const* d_in, const int* in_sizes, int n_in,
                              void* d_out, int out_size, void* d_ws, size_t ws_size,
                              hipStream_t stream) {
  const float* x   = (const float*)d_in[0];
  const float* Wf  = (const float*)d_in[1];
  const float* bfv = (const float*)d_in[2];
  const float* Wi  = (const float*)d_in[3];
  const float* biv = (const float*)d_in[4];
  const float* Wo  = (const float*)d_in[5];
  const float* bov = (const float*)d_in[6];
  const float* Wh  = (const float*)d_in[7];
  const float* bhv = (const float*)d_in[8];
  float* out = (float*)d_out;

  char* ws = (char*)d_ws;
  short* xbf   = (short*)ws;                         // 33,554,432 B
  short* sbufL = (short*)(ws + 33554432);            //  1,048,576 B (32 regions)
  short* sbufM = (short*)(ws + 34603008);            //    131,072 B (4 regions)
  u32*   arrL  = (u32*)(ws + 34734080);              //      4,096 B
  u32*   arrM  = (u32*)(ws + 34738176);              //        512 B
  u32*   vote  = (u32*)(ws + 34738688);              //        512 B
  u32*   vote2 = (u32*)(ws + 34739200);              //        512 B

  // zero flags + vote arrays (sbuf needs no init: slot for step l is fully
  // written before anyone reads it; probe phase re-inits arrL regardless)
  hipMemsetAsync(ws + 34734080, 0, 5632, stream);

  xprep_kernel<<<8192, 256, 0, stream>>>(x, xbf);

  lstm_persist<<<256, 256, 0, stream>>>(Wf, bfv, Wi, biv, Wo, bov, Wh, bhv,
                                        xbf, sbufL, sbufM, arrL, arrM,
                                        vote, vote2, out);
}

// Round 4
// 2969.667 us; speedup vs baseline: 5.9031x; 5.9031x over previous
//
#include <hip/hip_runtime.h>
#include <stdint.h>

typedef short short8 __attribute__((ext_vector_type(8)));
typedef float float4v __attribute__((ext_vector_type(4)));
typedef uint32_t u32;
typedef uint64_t u64;
typedef uint32_t u32x4 __attribute__((ext_vector_type(4)));

#define NSTEPS 512

struct U64x2 { u64 x, y; };

__device__ __forceinline__ unsigned short f2bf(float f) {
  unsigned u = __builtin_bit_cast(unsigned, f);
  u += 0x7fffu + ((u >> 16) & 1u);
  return (unsigned short)(u >> 16);
}

// ---- XCD-local transport --------------------------------------------------
// Writes: plain stores (L1 is write-through -> lands at the XCD's L2).
// Reads:  buffer_load ... sc0 (L1-bypass, serviced at L2; ISA ref S5 lists
//         sc0 as a valid MUBUF flag). Round 3 proved atomics work but their
//         RMW write-back flooded L2 (WRITE_SIZE 8.5 GB) -- loads don't.
// Flag post: buffer_atomic_swap (round-3-proven), once per block per step.
// The sc0-load semantics (does it really bypass L1?) are validated at
// runtime by an end-to-end probe; failure falls back to the sc1 baseline.
__device__ __forceinline__ u32x4 make_srsrc(const void* p, u32 bytes) {
  u32x4 r;
  u64 a = (u64)p;
  r.x = (u32)a;
  r.y = (u32)(a >> 32);   // stride=0
  r.z = bytes;            // num_records in bytes
  r.w = 0x00020000u;      // raw untyped dword access
  return r;
}
#define BLDX4(dst, voff, OFFSTR, rs)                                          \
  asm volatile("buffer_load_dwordx4 %0, %1, %2, 0 offen offset:" OFFSTR " sc0"\
               : "=v"(dst) : "v"(voff), "s"(rs))

__device__ __forceinline__ u32 ld_flag_sc0(u32x4 rs, u32 voff) {
  u32 v;
  asm volatile("buffer_load_dword %0, %1, %2, 0 offen sc0\n\t"
               "s_waitcnt vmcnt(0)"
               : "=v"(v) : "v"(voff), "s"(rs) : "memory");
  return v;
}
__device__ __forceinline__ void at_swap32(u32x4 rs, u32 voff, u32 v) {
  asm volatile("buffer_atomic_swap %0, %1, %2, 0 offen"
               :: "v"(v), "v"(voff), "s"(rs) : "memory");
}

// xbf layout (A-fragment swizzled): short8[ ((l*4+g)*16 + kk)*64 + lane ]
__global__ __launch_bounds__(256) void xprep_kernel(const float* __restrict__ x,
                                                    short* __restrict__ xbf) {
  unsigned tid = blockIdx.x * 256u + threadIdx.x;   // 2,097,152 total
  unsigned lane = tid & 63u;
  unsigned kk   = (tid >> 6) & 15u;
  unsigned g    = (tid >> 10) & 3u;
  unsigned l    = tid >> 12;
  unsigned m = lane & 15u, qo = lane >> 4;
  const float* src = x + (((size_t)(g * 16u + m) * 512u + l) * 512u + kk * 32u + qo * 8u);
  float4 a  = ((const float4*)src)[0];
  float4 b2 = ((const float4*)src)[1];
  short8 v;
  v[0] = (short)f2bf(a.x);  v[1] = (short)f2bf(a.y);
  v[2] = (short)f2bf(a.z);  v[3] = (short)f2bf(a.w);
  v[4] = (short)f2bf(b2.x); v[5] = (short)f2bf(b2.y);
  v[6] = (short)f2bf(b2.z); v[7] = (short)f2bf(b2.w);
  *(short8*)(xbf + (size_t)tid * 8u) = v;
}

// Persistent recurrent kernel with self-verifying XCD-local sync.
// grid=256: r=b&7 (XCD under round-robin -- round-3-verified); odd r exit;
// g=r>>1, c=b>>3. Prologue: (1) XCC_ID vote over sc1; (2) if uniform, PROBE
// the plain-store + sc0-load + atomic-flag transport end-to-end: two rounds
// over the SAME slot-0 addresses (round B overwrites round A, so a stale L1
// on sc0 loads is detected), with an sc1 ack barrier between rounds; (3)
// consensus over sc1. Failure anywhere -> baseline sc1 path (known 2.1 ms).
__global__ __launch_bounds__(256, 1) void lstm_persist(
    const float* __restrict__ Wfp, const float* __restrict__ bfp,
    const float* __restrict__ Wip, const float* __restrict__ bip,
    const float* __restrict__ Wop, const float* __restrict__ bop,
    const float* __restrict__ Whp, const float* __restrict__ bhp,
    const short* __restrict__ xbf,
    short* __restrict__ sbufL,       // 32 regions x [2][16][64][8] bf16
    short* __restrict__ sbufM,       // 4 regions (sc1 fallback), same shape
    u32* __restrict__ arrL,          // 32 regions x 32 flags (L2-local)
    u32* __restrict__ arrM,          // 4 x 32 flags (sc1)
    u32* __restrict__ vote,          // [4][32] xcd+1
    u32* __restrict__ vote2,         // [4][32] probe consensus (1 ok / 2 fail)
    u32* __restrict__ ack,           // [4][32] round-A read-done barrier
    float* __restrict__ out)         // [64][512][512] fp32
{
  __shared__ float gl[4 * 16 * 17];  // [gate][seq][h(+pad)]
  __shared__ int s_ok[4];

  const unsigned b = blockIdx.x;
  const unsigned r = b & 7u;
  if (r & 1u) return;                // spare residues exit whole-block
  const unsigned g = r >> 1;
  const unsigned c = b >> 3;
  const unsigned t = threadIdx.x;
  const unsigned w = t >> 6;
  const unsigned lane = t & 63u;
  const unsigned m = lane & 15u, qo = lane >> 4;

  // ---- vote phase (sc1, baseline-proven transport) ----
  if (t == 0) {
    u32 xcd = (u32)__builtin_amdgcn_s_getreg((31u << 11) | 20u) & 7u; // XCC_ID
    __hip_atomic_store(vote + g * 32u + c, xcd + 1u, __ATOMIC_RELAXED,
                       __HIP_MEMORY_SCOPE_AGENT);
  }
  u32 myv = 0;
  {
    const u32* vp = vote + g * 32u + (lane & 31u);
    long sp = 0;
    while ((myv = __hip_atomic_load(vp, __ATOMIC_RELAXED,
                                    __HIP_MEMORY_SCOPE_AGENT)) == 0u) {
      __builtin_amdgcn_s_sleep(2);
      if (++sp > 3000000L) break;
    }
  }
  u32 v0 = (u32)__builtin_amdgcn_readfirstlane((int)myv);
  int uniform = __all((int)(myv == v0)) && (v0 >= 1u) && (v0 <= 8u);
  s_ok[w] = uniform;
  __syncthreads();
  uniform = s_ok[0] & s_ok[1] & s_ok[2] & s_ok[3];
  __syncthreads();

  const unsigned region = uniform ? ((v0 - 1u) * 4u + g) : 0u;
  u32* sb32 = (u32*)(sbufL + (size_t)region * 16384u);  // 32 KiB region
  u32x4 srsD = make_srsrc(sb32, 32768u);
  u32x4 srsF = make_srsrc(arrL + region * 32u, 128u);
  short* sbM = sbufM + (size_t)g * 16384u;
  u32*   aM  = arrM + g * 32u;

  // ---- probe + consensus ----
  int local = 0;
  if (uniform) {
    int ok = 1;
#pragma unroll 1
    for (u32 R = 1; R <= 2; ++R) {
      // write pattern over slot 0 (same addresses both rounds!)
      if ((t & 1u) == 0u) {
        u32 idx = c * 128u + (t >> 1);
        sb32[idx] = (R << 20) ^ idx;
      }
      asm volatile("s_waitcnt vmcnt(0)" ::: "memory");
      __syncthreads();
      if (t == 0) at_swap32(srsF, c * 4u, R * 1000u + c);
      // observe all 32 tokens through the loop's exact poll sequence
      {
        u32 want = R * 1000u + (lane & 31u);
        long sp = 0;
        while (ld_flag_sc0(srsF, (lane & 31u) * 4u) != want) {
          __builtin_amdgcn_s_sleep(2);
          if (++sp > 30000L) { ok = 0; break; }
        }
      }
      __syncthreads();   // all 32 flags confirmed by some thread in block
      // read back pattern via sc0 loads (detects stale L1 in round 2)
      {
        u32x4 pv;
        BLDX4(pv, t * 64u, "0", srsD);
        asm volatile("s_waitcnt vmcnt(0)" ::: "memory");
#pragma unroll
        for (int j = 0; j < 4; j++)
          ok &= (pv[j] == ((R << 20) ^ (t * 16u + (u32)j)));
      }
      __syncthreads();
      if (R == 1) {
        // sc1 ack barrier: nobody overwrites round-A data while a slow
        // peer is still reading it (would look like corruption).
        if (t == 0)
          __hip_atomic_store(ack + g * 32u + c, 1u, __ATOMIC_RELAXED,
                             __HIP_MEMORY_SCOPE_AGENT);
        long sp = 0;
        while (__hip_atomic_load(ack + g * 32u + (lane & 31u), __ATOMIC_RELAXED,
                                 __HIP_MEMORY_SCOPE_AGENT) == 0u) {
          __builtin_amdgcn_s_sleep(2);
          if (++sp > 3000000L) break;
        }
        __syncthreads();
      }
    }
    // block verdict -> sc1 consensus across the group
    ok = __all(ok);
    s_ok[w] = ok;
    __syncthreads();
    int blk_ok = s_ok[0] & s_ok[1] & s_ok[2] & s_ok[3];
    if (t == 0)
      __hip_atomic_store(vote2 + g * 32u + c, blk_ok ? 1u : 2u,
                         __ATOMIC_RELAXED, __HIP_MEMORY_SCOPE_AGENT);
    u32 pv2 = 0;
    {
      long sp = 0;
      while ((pv2 = __hip_atomic_load(vote2 + g * 32u + (lane & 31u),
                                      __ATOMIC_RELAXED,
                                      __HIP_MEMORY_SCOPE_AGENT)) == 0u) {
        __builtin_amdgcn_s_sleep(2);
        if (++sp > 3000000L) { pv2 = 2u; break; }
      }
    }
    int lw = __all((int)(pv2 == 1u));
    __syncthreads();
    s_ok[w] = lw;
    __syncthreads();
    local = s_ok[0] & s_ok[1] & s_ok[2] & s_ok[3];
    // reset tokens -> 0 (doubles as cross-replay flag init); wait until all
    // tokens gone (<1000 also accepts early step-posts 1..512).
    if (local) {
      if (t == 0) {
        at_swap32(srsF, c * 4u, 0u);
        asm volatile("s_waitcnt vmcnt(0)" ::: "memory");
      }
      long sp = 0;
      while (ld_flag_sc0(srsF, (lane & 31u) * 4u) >= 1000u) {
        __builtin_amdgcn_s_sleep(2);
        if (++sp > 100000L) break;
      }
    }
    __syncthreads();
  }

  const float* Wsrc = (w == 0) ? Wfp : (w == 1) ? Wip : (w == 2) ? Wop : Whp;
  const float* bsrc = (w == 0) ? bfp : (w == 1) ? bip : (w == 2) ? bop : bhp;

  // ---- one-time: this wave's B-fragments (W rows c*16+[0,16)) in registers.
  short8 wsf[16], wnf[16];
  {
    const float* wrow = Wsrc + (size_t)(c * 16u + m) * 1024u + qo * 8u;
#pragma unroll
    for (int kk = 0; kk < 16; kk++) {
      const float* p = wrow + kk * 32;
      short8 vs, vn;
#pragma unroll
      for (int j = 0; j < 8; j++) {
        vs[j] = (short)f2bf(p[j]);          // W_short = cols [0,512)
        vn[j] = (short)f2bf(p[512 + j]);    // W_now   = cols [512,1024)
      }
      wsf[kk] = vs;
      wnf[kk] = vn;
    }
  }
  const float bias = bsrc[c * 16u + m];

  // elementwise ownership: thread t <-> (seq mm, h hh); state in register.
  const unsigned mm = t >> 4, hh = t & 15u;
  float longv = 0.f;
  float* outp = out + (size_t)(g * 16u + mm) * (512u * 512u) + (c * 16u + hh);

  // store slot (u32 = 2 adjacent bf16), even threads only
  unsigned slot_off;                 // u32 index within a 16 KiB slot
  {
    unsigned k   = c * 16u + hh;     // hh even for storing threads
    unsigned kk2 = k >> 5;
    unsigned lw2 = ((k >> 3) & 3u) * 16u + mm;
    unsigned jj  = k & 7u;
    slot_off = (kk2 * 64u + lw2) * 4u + (jj >> 1);
  }
  u32* sdstM = (u32*)sbM + slot_off;

  for (int l = 0; l < NSTEPS; l++) {
    // ---- x-part: independent of peers, runs before the wait.
    const short8* xt = (const short8*)xbf + ((size_t)(l * 4 + g) * 16u) * 64u + lane;
    short8 xa[16];
#pragma unroll
    for (int kk = 0; kk < 16; kk++) xa[kk] = xt[(size_t)kk * 64u];

    float4v acc[4];
    {
      float4v bb = {bias, bias, bias, bias};
      float4v zz = {0.f, 0.f, 0.f, 0.f};
      acc[0] = bb; acc[1] = zz; acc[2] = zz; acc[3] = zz;
    }
#pragma unroll
    for (int kk = 0; kk < 16; kk++)
      acc[kk & 3] = __builtin_amdgcn_mfma_f32_16x16x32_bf16(xa[kk], wnf[kk], acc[kk & 3], 0, 0, 0);

    if (l > 0) {
      // ---- wait for all 32 chunks to post step l-1.
      if (lane < 32u) {
        long spins = 0;
        if (local) {
          while (ld_flag_sc0(srsF, lane * 4u) < (u32)l) {
            __builtin_amdgcn_s_sleep(1);
            if (++spins > (100LL * 1000 * 1000)) break;
          }
        } else {
          const u32* fp = aM + lane;
          while (__hip_atomic_load(fp, __ATOMIC_RELAXED,
                                   __HIP_MEMORY_SCOPE_AGENT) < (u32)l) {
            __builtin_amdgcn_s_sleep(1);
            if (++spins > (100LL * 1000 * 1000)) break;
          }
        }
      }

      // ---- recurrent part: short^{l-1} A-fragments (plain sc0 loads).
      const unsigned slotB = ((unsigned)(l - 1) & 1u) * 16384u;
      u32x4 fr[16];
      if (local) {
        u32 vb = slotB + lane * 16u;
#pragma unroll
        for (int q = 0; q < 4; q++) {
          u32 vq = vb + (u32)q * 4096u;
          BLDX4(fr[q * 4 + 0], vq, "0",    srsD);
          BLDX4(fr[q * 4 + 1], vq, "1024", srsD);
          BLDX4(fr[q * 4 + 2], vq, "2048", srsD);
          BLDX4(fr[q * 4 + 3], vq, "3072", srsD);
        }
      } else {
        const u64* stM = (const u64*)sbM + (size_t)(slotB >> 3) + (size_t)lane * 2u;
#pragma unroll
        for (int kk = 0; kk < 16; kk++) {
          U64x2 p;
          p.x = __hip_atomic_load(stM + (size_t)kk * 128u, __ATOMIC_RELAXED,
                                  __HIP_MEMORY_SCOPE_AGENT);
          p.y = __hip_atomic_load(stM + (size_t)kk * 128u + 1u, __ATOMIC_RELAXED,
                                  __HIP_MEMORY_SCOPE_AGENT);
          fr[kk] = __builtin_bit_cast(u32x4, p);
        }
      }
      asm volatile("s_waitcnt vmcnt(0)" ::: "memory");
      __builtin_amdgcn_sched_barrier(0);

#pragma unroll
      for (int kk = 0; kk < 16; kk++) {
        short8 sa = __builtin_bit_cast(short8, fr[kk]);
        acc[kk & 3] = __builtin_amdgcn_mfma_f32_16x16x32_bf16(sa, wsf[kk], acc[kk & 3], 0, 0, 0);
      }
    }

    float4v tot = (acc[0] + acc[1]) + (acc[2] + acc[3]);
    // C/D layout: col = lane&15 (gate row/h), row = qo*4 + r (seq)
#pragma unroll
    for (int rr = 0; rr < 4; rr++)
      gl[(w * 16u + qo * 4u + (unsigned)rr) * 17u + m] = tot[rr];
    __syncthreads();

    // ---- elementwise update (all 256 threads: 16 seq x 16 h)
    float fg = gl[(0 * 16 + mm) * 17 + hh];
    float ig = gl[(1 * 16 + mm) * 17 + hh];
    float og = gl[(2 * 16 + mm) * 17 + hh];
    float hg = gl[(3 * 16 + mm) * 17 + hh];   // no activation on h (matches ref)
    fg = 1.f / (1.f + __expf(-fg));
    ig = 1.f / (1.f + __expf(-ig));
    og = 1.f / (1.f + __expf(-og));
    longv = fg * longv + ig * hg;
    float e  = __expf(-2.f * fabsf(longv));
    float th = (1.f - e) / (1.f + e);
    th = (longv < 0.f) ? -th : th;
    float sh = og * th;

    // pack adjacent-h pair into u32, even threads store (plain, write-through)
    unsigned short mybf = f2bf(sh);
    float shn = __shfl_xor(sh, 1);
    if ((t & 1u) == 0u) {
      u32 val = (u32)mybf | ((u32)f2bf(shn) << 16);
      if (local) {
        sb32[((unsigned)l & 1u) * 4096u + slot_off] = val;
      } else {
        __hip_atomic_store(sdstM + ((size_t)((unsigned)l & 1u)) * 4096u, val,
                           __ATOMIC_RELAXED, __HIP_MEMORY_SCOPE_AGENT);
      }
    }
    // data-store ack (L2) before the barrier; then flag post.
    asm volatile("s_waitcnt vmcnt(0)" ::: "memory");
    __syncthreads();
    if (t == 0) {
      if (local) {
        at_swap32(srsF, c * 4u, (u32)(l + 1));
      } else {
        __hip_atomic_store(aM + c, (u32)(l + 1), __ATOMIC_RELAXED,
                           __HIP_MEMORY_SCOPE_AGENT);
      }
    }

    // output store AFTER the flag post: keeps it off the sync critical path
    outp[(size_t)l * 512u] = sh;
  }
}

extern "C" void kernel_launch(void* const* d_in, const int* in_sizes, int n_in,
                              void* d_out, int out_size, void* d_ws, size_t ws_size,
                              hipStream_t stream) {
  const float* x   = (const float*)d_in[0];
  const float* Wf  = (const float*)d_in[1];
  const float* bfv = (const float*)d_in[2];
  const float* Wi  = (const float*)d_in[3];
  const float* biv = (const float*)d_in[4];
  const float* Wo  = (const float*)d_in[5];
  const float* bov = (const float*)d_in[6];
  const float* Wh  = (const float*)d_in[7];
  const float* bhv = (const float*)d_in[8];
  float* out = (float*)d_out;

  char* ws = (char*)d_ws;
  short* xbf   = (short*)ws;                         // 33,554,432 B
  short* sbufL = (short*)(ws + 33554432);            //  1,048,576 B (32 regions)
  short* sbufM = (short*)(ws + 34603008);            //    131,072 B (4 regions)
  u32*   arrL  = (u32*)(ws + 34734080);              //      4,096 B (probe-managed)
  u32*   arrM  = (u32*)(ws + 34738176);              //        512 B
  u32*   vote  = (u32*)(ws + 34738688);              //        512 B
  u32*   vote2 = (u32*)(ws + 34739200);              //        512 B
  u32*   ack   = (u32*)(ws + 34739712);              //        512 B

  // zero sc1-side flags + vote/consensus/ack arrays (arrL is re-initialized
  // by the probe handshake itself, so replays never depend on memset-vs-L2)
  hipMemsetAsync(ws + 34738176, 0, 2048, stream);

  xprep_kernel<<<8192, 256, 0, stream>>>(x, xbf);

  lstm_persist<<<256, 256, 0, stream>>>(Wf, bfv, Wi, biv, Wo, bov, Wh, bhv,
                                        xbf, sbufL, sbufM, arrL, arrM,
                                        vote, vote2, ack, out);
}

// Round 6
// 1749.506 us; speedup vs baseline: 10.0200x; 1.6974x over previous
//
#include <hip/hip_runtime.h>
#include <stdint.h>

typedef short short8 __attribute__((ext_vector_type(8)));
typedef float float4v __attribute__((ext_vector_type(4)));
typedef uint32_t u32;
typedef uint64_t u64;

#define NSTEPS 512

struct U64x2 { u64 x, y; };

__device__ __forceinline__ unsigned short f2bf(float f) {
  unsigned u = __builtin_bit_cast(unsigned, f);
  u += 0x7fffu + ((u >> 16) & 1u);
  return (unsigned short)(u >> 16);
}

// xbf layout (A-fragment swizzled): short8[ ((l*4+g)*16 + kk)*64 + lane ]
// element (l, g, m, k):  m = lane&15, k = kk*32 + (lane>>4)*8 + j
__global__ __launch_bounds__(256) void xprep_kernel(const float* __restrict__ x,
                                                    short* __restrict__ xbf) {
  unsigned tid = blockIdx.x * 256u + threadIdx.x;   // 2,097,152 total
  unsigned lane = tid & 63u;
  unsigned kk   = (tid >> 6) & 15u;
  unsigned g    = (tid >> 10) & 3u;
  unsigned l    = tid >> 12;
  unsigned m = lane & 15u, qo = lane >> 4;
  const float* src = x + (((size_t)(g * 16u + m) * 512u + l) * 512u + kk * 32u + qo * 8u);
  float4 a  = ((const float4*)src)[0];
  float4 b2 = ((const float4*)src)[1];
  short8 v;
  v[0] = (short)f2bf(a.x);  v[1] = (short)f2bf(a.y);
  v[2] = (short)f2bf(a.z);  v[3] = (short)f2bf(a.w);
  v[4] = (short)f2bf(b2.x); v[5] = (short)f2bf(b2.y);
  v[6] = (short)f2bf(b2.z); v[7] = (short)f2bf(b2.w);
  *(short8*)(xbf + (size_t)tid * 8u) = v;
}

// Persistent recurrent kernel (round-0 protocol: sc1 flags + sc1 state).
// NEW vs round 0: the 16 KB state block is ingested ONCE PER BLOCK instead
// of once per wave. Each wave sc1-loads only its 4 kk-rows (8 u64 loads),
// ds_writes them into a shared LDS tile, one barrier, then all 4 waves
// ds_read_b128 their MFMA fragments from LDS. This cuts the per-step
// hot-set read traffic (128 waves x 16 KB = 2 MB/group/step, all hitting
// the SAME 128 cache lines at the coherence point) by 4x -- the round-3/4
// evidence says per-line service throughput on that hot set, not sync
// latency, is the dominant cost of a step.
__global__ __launch_bounds__(256, 1) void lstm_persist(
    const float* __restrict__ Wfp, const float* __restrict__ bfp,
    const float* __restrict__ Wip, const float* __restrict__ bip,
    const float* __restrict__ Wop, const float* __restrict__ bop,
    const float* __restrict__ Whp, const float* __restrict__ bhp,
    const short* __restrict__ xbf,
    short* __restrict__ sbuf,        // [2][4][16kk][64lane][8] bf16 (A-swizzled)
    u32* __restrict__ arrive,        // [4][32]: steps completed by chunk
    float* __restrict__ out)         // [64][512][512] fp32
{
  __shared__ float gl[4 * 16 * 17];  // [gate][seq][h(+pad)]
  __shared__ short ss[16 * 64 * 8];  // staged state tile: [kk][lane][8] bf16

  const unsigned b = blockIdx.x;
  const unsigned g = (b & 7u) >> 1;
  const unsigned c = ((b >> 3) << 1) | (b & 1u);
  const unsigned t = threadIdx.x;
  const unsigned w = t >> 6;
  const unsigned lane = t & 63u;
  const unsigned m = lane & 15u, qo = lane >> 4;

  const float* Wsrc = (w == 0) ? Wfp : (w == 1) ? Wip : (w == 2) ? Wop : Whp;
  const float* bsrc = (w == 0) ? bfp : (w == 1) ? bip : (w == 2) ? bop : bhp;

  // ---- one-time: this wave's B-fragments (W rows c*16+[0,16)) into registers.
  // B[k][n]: n = lane&15 (gate row), k = kk*32 + qo*8 + j.
  short8 wsf[16], wnf[16];
  {
    const float* wrow = Wsrc + (size_t)(c * 16u + m) * 1024u + qo * 8u;
#pragma unroll
    for (int kk = 0; kk < 16; kk++) {
      const float* p = wrow + kk * 32;
      short8 vs, vn;
#pragma unroll
      for (int j = 0; j < 8; j++) {
        vs[j] = (short)f2bf(p[j]);          // W_short = cols [0,512)
        vn[j] = (short)f2bf(p[512 + j]);    // W_now   = cols [512,1024)
      }
      wsf[kk] = vs;
      wnf[kk] = vn;
    }
  }
  const float bias = bsrc[c * 16u + m];

  // elementwise ownership: thread t <-> (seq mm, h hh); state in register.
  const unsigned mm = t >> 4, hh = t & 15u;
  float longv = 0.f;
  float* outp = out + (size_t)(g * 16u + mm) * (512u * 512u) + (c * 16u + hh);

  // precomputed sbuf store slot (u32 = 2 adjacent bf16), even threads only
  u32* sdst;
  {
    unsigned k   = c * 16u + hh;       // hh even for storing threads
    unsigned kk2 = k >> 5;
    unsigned lw  = ((k >> 3) & 3u) * 16u + mm;
    unsigned jj  = k & 7u;
    sdst = (u32*)sbuf + ((((size_t)g) * 16u + kk2) * 64u + lw) * 4u + (jj >> 1);
  }
  const size_t sslot = (size_t)4u * 16u * 64u * 4u;  // u32s per buffer slot

  const u32* fl = arrive + g * 32u;

  for (int l = 0; l < NSTEPS; l++) {
    // ---- x-part: independent of peers, runs before the wait. Plain
    // cacheable loads: the 16 KB tile is L1/L2-absorbed across waves.
    const short8* xt = (const short8*)xbf + ((size_t)(l * 4 + g) * 16u) * 64u + lane;
    short8 xa[16];
#pragma unroll
    for (int kk = 0; kk < 16; kk++) xa[kk] = xt[(size_t)kk * 64u];

    float4v acc[4];
    {
      float4v bb = {bias, bias, bias, bias};
      float4v zz = {0.f, 0.f, 0.f, 0.f};
      acc[0] = bb; acc[1] = zz; acc[2] = zz; acc[3] = zz;
    }
#pragma unroll
    for (int kk = 0; kk < 16; kk++)
      acc[kk & 3] = __builtin_amdgcn_mfma_f32_16x16x32_bf16(xa[kk], wnf[kk], acc[kk & 3], 0, 0, 0);

    if (l > 0) {
      // ---- each wave independently waits for all 32 chunks to post l-1.
      if (lane < 32u) {
        long spins = 0;
        while (__hip_atomic_load(fl + lane, __ATOMIC_RELAXED,
                                 __HIP_MEMORY_SCOPE_AGENT) < (u32)l) {
          __builtin_amdgcn_s_sleep(1);
          if (++spins > (100LL * 1000 * 1000)) break;  // bail -> wrong, not hung
        }
      }

      // ---- state ingest, split across waves: wave w sc1-loads rows
      // kk = w*4..w*4+4 (8 u64 coherent loads) and shares them via LDS.
      const u64* stM = (const u64*)sbuf +
                       ((size_t)(((unsigned)(l - 1) & 1u) * 4u + g) * 16u) * 64u * 2u +
                       (size_t)lane * 2u;
      U64x2 st4[4];
#pragma unroll
      for (int q = 0; q < 4; q++) {
        unsigned kk = w * 4u + (unsigned)q;
        st4[q].x = __hip_atomic_load(stM + (size_t)kk * 128u, __ATOMIC_RELAXED,
                                     __HIP_MEMORY_SCOPE_AGENT);
        st4[q].y = __hip_atomic_load(stM + (size_t)kk * 128u + 1u, __ATOMIC_RELAXED,
                                     __HIP_MEMORY_SCOPE_AGENT);
      }
#pragma unroll
      for (int q = 0; q < 4; q++) {
        unsigned kk = w * 4u + (unsigned)q;
        *(short8*)(ss + kk * 512u + lane * 8u) = __builtin_bit_cast(short8, st4[q]);
      }
      __syncthreads();   // staged tile visible to all 4 waves

#pragma unroll
      for (int kk = 0; kk < 16; kk++) {
        short8 sa = *(const short8*)(ss + (unsigned)kk * 512u + lane * 8u);
        acc[kk & 3] = __builtin_amdgcn_mfma_f32_16x16x32_bf16(sa, wsf[kk], acc[kk & 3], 0, 0, 0);
      }
    }

    float4v tot = (acc[0] + acc[1]) + (acc[2] + acc[3]);
    // C/D layout: col = lane&15 (gate row/h), row = qo*4 + r (seq)
#pragma unroll
    for (int r = 0; r < 4; r++)
      gl[(w * 16u + qo * 4u + (unsigned)r) * 17u + m] = tot[r];
    __syncthreads();

    // ---- elementwise update (all 256 threads: 16 seq x 16 h)
    float fg = gl[(0 * 16 + mm) * 17 + hh];
    float ig = gl[(1 * 16 + mm) * 17 + hh];
    float og = gl[(2 * 16 + mm) * 17 + hh];
    float hg = gl[(3 * 16 + mm) * 17 + hh];   // no activation on h (matches ref)
    fg = 1.f / (1.f + __expf(-fg));
    ig = 1.f / (1.f + __expf(-ig));
    og = 1.f / (1.f + __expf(-og));
    longv = fg * longv + ig * hg;
    float e  = __expf(-2.f * fabsf(longv));
    float th = (1.f - e) / (1.f + e);
    th = (longv < 0.f) ? -th : th;
    float sh = og * th;

    // pack adjacent-h pair into u32, even threads store coherently (sc1)
    unsigned short mybf = f2bf(sh);
    float shn = __shfl_xor(sh, 1);
    if ((t & 1u) == 0u) {
      u32 val = (u32)mybf | ((u32)f2bf(shn) << 16);
      __hip_atomic_store(sdst + ((size_t)((unsigned)l & 1u)) * sslot, val,
                         __ATOMIC_RELAXED, __HIP_MEMORY_SCOPE_AGENT);
    }
    // data-store ack drain before the barrier; then flag post.
    asm volatile("s_waitcnt vmcnt(0)" ::: "memory");
    __syncthreads();
    if (t == 0)
      __hip_atomic_store((u32*)(arrive + g * 32u + c), (u32)(l + 1),
                         __ATOMIC_RELAXED, __HIP_MEMORY_SCOPE_AGENT);

    // output store AFTER the flag post: keeps it off the sync critical path
    outp[(size_t)l * 512u] = sh;
  }
}

extern "C" void kernel_launch(void* const* d_in, const int* in_sizes, int n_in,
                              void* d_out, int out_size, void* d_ws, size_t ws_size,
                              hipStream_t stream) {
  const float* x   = (const float*)d_in[0];
  const float* Wf  = (const float*)d_in[1];
  const float* bfv = (const float*)d_in[2];
  const float* Wi  = (const float*)d_in[3];
  const float* biv = (const float*)d_in[4];
  const float* Wo  = (const float*)d_in[5];
  const float* bov = (const float*)d_in[6];
  const float* Wh  = (const float*)d_in[7];
  const float* bhv = (const float*)d_in[8];
  float* out = (float*)d_out;

  char* ws = (char*)d_ws;
  short* xbf    = (short*)ws;                                // 33,554,432 B
  short* sbuf   = (short*)(ws + 33554432);                   //    131,072 B
  u32*   arrive = (u32*)(ws + 33554432 + 131072);            //        512 B

  // zero the arrival counters (sbuf needs no init: slot for step l is fully
  // written before anyone reads it; step 0 has no recurrent read)
  hipMemsetAsync(ws + 33554432 + 131072, 0, 512, stream);

  xprep_kernel<<<8192, 256, 0, stream>>>(x, xbf);

  lstm_persist<<<128, 256, 0, stream>>>(Wf, bfv, Wi, biv, Wo, bov, Wh, bhv,
                                        xbf, sbuf, arrive, out);
}